// Round 18
// baseline (196.216 us; speedup 1.0000x reference)
//
#include <hip/hip_runtime.h>
#include <hip/hip_bf16.h>

#define D_MODEL 1024
#define N_HEAD  16
#define D_K     64
#define MAX_LEN 1000
#define B_      4
#define S_      1000
#define S_PAD   1024
#define M_PAD   (B_ * S_PAD)       // 4096
#define M_REAL  (B_ * S_)          // 4000
#define LN_EPS  1e-5f
#define SCALE_L2E 0.1803368801111204f   // 0.125 * log2(e)
#define REL_ROWS (2*MAX_LEN-1)     // 1999

typedef __attribute__((ext_vector_type(8))) short short8;
typedef __attribute__((ext_vector_type(4))) float f32x4;

__device__ __forceinline__ unsigned short f2b(float f) {
    unsigned u = __builtin_bit_cast(unsigned, f);
    u = (u + 0x7FFFu + ((u >> 16) & 1u)) >> 16;
    return (unsigned short)u;
}

__device__ __forceinline__ unsigned short f2b_trunc(float f) {
    return (unsigned short)(__builtin_bit_cast(unsigned, f) >> 16);
}

__device__ __forceinline__ float b2f(unsigned short u) {
    return __builtin_bit_cast(float, (unsigned)u << 16);
}

__device__ __forceinline__ f32x4 mfma16(short8 a, short8 b, f32x4 c) {
    return __builtin_amdgcn_mfma_f32_16x16x32_bf16(a, b, c, 0, 0, 0);
}

__device__ __forceinline__ void gload_lds16(const void* g, void* l) {
    __builtin_amdgcn_global_load_lds(
        (const __attribute__((address_space(1))) unsigned int*)g,
        (__attribute__((address_space(3))) unsigned int*)l, 16, 0, 0);
}

// DPP row_ror rotation within 16-lane rows (VALU, not LDS pipe)
#define DPPROR(x, S) __builtin_bit_cast(float, __builtin_amdgcn_update_dpp( \
        0, __builtin_bit_cast(int, (x)), 0x120 | (S), 0xF, 0xF, false))

// ---------------- merged cvt (5 weight tensors) + LayerNorm x3, ONE launch ----------------
__global__ void prep_all(const float* __restrict__ wq, const float* __restrict__ wk,
                         const float* __restrict__ wv, const float* __restrict__ wo,
                         const float* __restrict__ rel,
                         unsigned short* __restrict__ wqb, unsigned short* __restrict__ wkb,
                         unsigned short* __restrict__ wvb, unsigned short* __restrict__ wob,
                         unsigned short* __restrict__ relb,
                         const float* __restrict__ xq, const float* __restrict__ xk,
                         const float* __restrict__ xv, const float* __restrict__ g,
                         const float* __restrict__ beta,
                         unsigned short* __restrict__ yq, unsigned short* __restrict__ yk,
                         unsigned short* __restrict__ yv) {
    __shared__ float rs[4], rq[4];
    int bid = blockIdx.x;
    int tid = threadIdx.x;
    if (bid < 5120) {
        int y = bid >> 10;
        const float* in; unsigned short* out; int n4;
        switch (y) {
            case 0: in = wq; out = wqb; n4 = 262144; break;
            case 1: in = wk; out = wkb; n4 = 262144; break;
            case 2: in = wv; out = wvb; n4 = 262144; break;
            case 3: in = wo; out = wob; n4 = 262144; break;
            default: in = rel; out = relb; n4 = REL_ROWS * D_K / 4; break;
        }
        int i = (bid & 1023) * 256 + tid;
        if (i >= n4) return;
        float4 v = ((const float4*)in)[i];
        ushort4 o;
        o.x = f2b(v.x); o.y = f2b(v.y); o.z = f2b(v.z); o.w = f2b(v.w);
        ((ushort4*)out)[i] = o;
        return;
    }
    int r2 = bid - 5120;
    int which = r2 >> 12;          // 0..2
    int r = r2 & 4095;             // padded row index
    const float* x = which == 0 ? xq : which == 1 ? xk : xv;
    unsigned short* y = which == 0 ? yq : which == 1 ? yk : yv;
    int b = r >> 10, i = r & 1023;
    unsigned short* yr = y + (size_t)r * D_MODEL;
    if (i >= S_) {
#pragma unroll
        for (int l = 0; l < 4; ++l) yr[tid + l * 256] = 0;
        return;
    }
    const float* xr = x + ((size_t)b * S_ + i) * D_MODEL;
    float v[4];
    float s = 0.f, sq = 0.f;
#pragma unroll
    for (int l = 0; l < 4; ++l) {
        v[l] = xr[tid + l * 256];
        s += v[l];
        sq += v[l] * v[l];
    }
#pragma unroll
    for (int o = 32; o > 0; o >>= 1) {
        s += __shfl_down(s, o, 64);
        sq += __shfl_down(sq, o, 64);
    }
    if ((tid & 63) == 0) { rs[tid >> 6] = s; rq[tid >> 6] = sq; }
    __syncthreads();
    if (tid == 0) {
        rs[0] = rs[0] + rs[1] + rs[2] + rs[3];
        rq[0] = rq[0] + rq[1] + rq[2] + rq[3];
    }
    __syncthreads();
    float mu = rs[0] * (1.0f / D_MODEL);
    float var = rq[0] * (1.0f / D_MODEL) - mu * mu;
    float rstd = rsqrtf(var + LN_EPS);
#pragma unroll
    for (int l = 0; l < 4; ++l) {
        int c = tid + l * 256;
        yr[c] = f2b((v[l] - mu) * rstd * g[c] + beta[c]);
    }
}

// ---------------- GEMM core: double-buffered K-loop ----------------
// MODE 0: head layout; MODE 3: head layout PRESCALED by SCALE_L2E (for Q);
// MODE 1: transposed head; MODE 2: fp32 +resid.
template<int MODE>
__device__ __forceinline__ void gemm_body(
        const unsigned short* __restrict__ X, const unsigned short* __restrict__ W,
        const float* __restrict__ bias, const float* __restrict__ resid,
        unsigned short* __restrict__ Yb, float* __restrict__ Yf,
        unsigned short* As, unsigned short* Bs, int row0, int col0) {
    int tid = threadIdx.x;
    int lane = tid & 63, w = tid >> 6;
    int wr = w >> 1, wc = w & 1;
    int fr = lane & 15, fk = (lane >> 4) * 8;

    f32x4 acc[4][4];
#pragma unroll
    for (int fm = 0; fm < 4; ++fm)
#pragma unroll
        for (int fn = 0; fn < 4; ++fn) acc[fm][fn] = (f32x4)0.f;

    int c0 = (w * 2 + 0) * 64 + lane;
    int c1 = (w * 2 + 1) * 64 + lane;
    const unsigned short* xs0 = X + (size_t)(row0 + (c0 >> 2)) * 1024 + (c0 & 3) * 8;
    const unsigned short* xs1 = X + (size_t)(row0 + (c1 >> 2)) * 1024 + (c1 & 3) * 8;
    const unsigned short* ws0 = W + (size_t)(col0 + (c0 >> 2)) * 1024 + (c0 & 3) * 8;
    const unsigned short* ws1 = W + (size_t)(col0 + (c1 >> 2)) * 1024 + (c1 & 3) * 8;
    int do0 = (w * 2 + 0) * 512;
    int do1 = (w * 2 + 1) * 512;

    auto stage = [&](int buf, int k0) {
        gload_lds16(xs0 + k0, As + buf * 4096 + do0);
        gload_lds16(xs1 + k0, As + buf * 4096 + do1);
        gload_lds16(ws0 + k0, Bs + buf * 4096 + do0);
        gload_lds16(ws1 + k0, Bs + buf * 4096 + do1);
    };

    stage(0, 0);

    for (int it = 0; it < 32; ++it) {
        __syncthreads();
        if (it < 31) stage((it & 1) ^ 1, (it + 1) * 32);

        const unsigned short* Ab = As + (it & 1) * 4096;
        const unsigned short* Bb = Bs + (it & 1) * 4096;
        short8 a[4], b[4];
#pragma unroll
        for (int fm = 0; fm < 4; ++fm)
            a[fm] = *(const short8*)(Ab + (wr * 64 + fm * 16 + fr) * 32 + fk);
#pragma unroll
        for (int fn = 0; fn < 4; ++fn)
            b[fn] = *(const short8*)(Bb + (wc * 64 + fn * 16 + fr) * 32 + fk);
#pragma unroll
        for (int fm = 0; fm < 4; ++fm)
#pragma unroll
            for (int fn = 0; fn < 4; ++fn)
                acc[fm][fn] = mfma16(a[fm], b[fn], acc[fm][fn]);
    }

#pragma unroll
    for (int fm = 0; fm < 4; ++fm) {
#pragma unroll
        for (int fn = 0; fn < 4; ++fn) {
            int cg = col0 + wc * 64 + fn * 16 + fr;
            float bv = bias[cg];
#pragma unroll
            for (int r = 0; r < 4; ++r) {
                int rg = row0 + wr * 64 + fm * 16 + (lane >> 4) * 4 + r;
                float val = acc[fm][fn][r] + bv;
                int b_ = rg >> 10, i = rg & 1023;
                if (MODE == 0 || MODE == 3) {
                    if (MODE == 3) val *= SCALE_L2E;
                    int h = cg >> 6, d = cg & 63;
                    Yb[(((size_t)(b_ * N_HEAD + h)) * S_PAD + i) * D_K + d] = f2b(val);
                } else if (MODE == 1) {
                    int h = cg >> 6, d = cg & 63;
                    Yb[(((size_t)(b_ * N_HEAD + h)) * D_K + d) * S_PAD + i] = f2b(val);
                } else {
                    if (i < S_) {
                        size_t orow = (size_t)b_ * S_ + i;
                        Yf[orow * 1024 + cg] = val + resid[orow * 1024 + cg];
                    }
                }
            }
        }
    }
}

// merged Q/K/V projections: grid (8, 32, 3); Q prescaled (MODE 3)
__global__ __launch_bounds__(256) void gemm_qkv(
        const unsigned short* __restrict__ qn, const unsigned short* __restrict__ kn,
        const unsigned short* __restrict__ vn,
        const unsigned short* __restrict__ wqb, const unsigned short* __restrict__ wkb,
        const unsigned short* __restrict__ wvb,
        const float* __restrict__ bq, const float* __restrict__ bk,
        const float* __restrict__ bv,
        unsigned short* __restrict__ qh, unsigned short* __restrict__ kh,
        unsigned short* __restrict__ vt) {
    __shared__ __align__(16) unsigned short As[2][128 * 32];
    __shared__ __align__(16) unsigned short Bs[2][128 * 32];
    int fid = blockIdx.x + (blockIdx.y << 3) + (blockIdx.z << 8);   // [0,768)
    int swz = (fid & 7) * 96 + (fid >> 3);                          // bijective
    int bz = swz >> 8;
    int rem = swz & 255;
    int row0 = (rem >> 3) * 128, col0 = (rem & 7) * 128;
    if (bz == 0)
        gemm_body<3>(qn, wqb, bq, nullptr, qh, nullptr, As[0], Bs[0], row0, col0);
    else if (bz == 1)
        gemm_body<0>(kn, wkb, bk, nullptr, kh, nullptr, As[0], Bs[0], row0, col0);
    else
        gemm_body<1>(vn, wvb, bv, nullptr, vt, nullptr, As[0], Bs[0], row0, col0);
}

// final output projection + residual
__global__ __launch_bounds__(256) void gemm_out(
        const unsigned short* __restrict__ X, const unsigned short* __restrict__ W,
        const float* __restrict__ bias, const float* __restrict__ resid,
        float* __restrict__ Yf) {
    __shared__ __align__(16) unsigned short As[2][128 * 32];
    __shared__ __align__(16) unsigned short Bs[2][128 * 32];
    int fid = blockIdx.x + (blockIdx.y << 3);       // [0,256)
    int swz = (fid & 7) * 32 + (fid >> 3);          // bijective
    int row0 = (swz >> 3) * 128, col0 = (swz & 7) * 128;
    gemm_body<2>(X, W, bias, resid, nullptr, Yf, As[0], Bs[0], row0, col0);
}

// ---------------- Flash attention: fused pair + 1-iter-ahead QR pipeline ----------------
// QR for iteration it+1 is spilled DURING iteration it (QR depends only on Q,rel).
// Gather at iter it reads parity it&1 (written last iter -> no lgkm dependency).
// QRT=12: b64-aligned (24B*col + 8B*rgrp), 8-distinct-bank spill writes.
#define QRT 12
#define QPR 1152  // region size: max(80*12=960, 16*72=1152); P shares CUR region
#define PW  72
__device__ __forceinline__ void spill_qr(
        unsigned short* __restrict__ dst, const short8 (*rlf)[2],
        short8 aq0, short8 aq1, int fr, int rgrp) {
#pragma unroll
    for (int fu = 0; fu < 5; ++fu) {
        f32x4 qr = (f32x4)0.f;
        qr = mfma16(aq0, rlf[fu][0], qr);
        qr = mfma16(aq1, rlf[fu][1], qr);
        unsigned lo = ((unsigned)f2b_trunc(qr[1]) << 16) | f2b_trunc(qr[0]);
        unsigned hi = ((unsigned)f2b_trunc(qr[3]) << 16) | f2b_trunc(qr[2]);
        *(uint2*)(dst + (fu * 16 + fr) * QRT + rgrp) = uint2{lo, hi};
    }
}

__device__ __forceinline__ void attn_pair(
        const unsigned short* __restrict__ Kc, const unsigned short* __restrict__ Vc,
        unsigned short* __restrict__ curA, unsigned short* __restrict__ curB,
        unsigned short* __restrict__ nxtA, unsigned short* __restrict__ nxtB,
        const short8 (*rlnx)[2],   // rel fragments for NEXT iter (a: 0..4, b: 1..5)
        short8 aqa0, short8 aqa1, short8 aqb0, short8 aqb1,
        f32x4* accOa, f32x4* accOb,
        float* mra, float* lra, float* mrb, float* lrb,
        bool mask_needed, int j0, int fr, int fk8, int rgrp, int rsw) {
    // ---- QK^T both slabs, shared K fragments ----
    f32x4 accS0[4], accS1[4];
#pragma unroll
    for (int fj = 0; fj < 4; ++fj) { accS0[fj] = (f32x4)0.f; accS1[fj] = (f32x4)0.f; }
    __builtin_amdgcn_s_setprio(1);
#pragma unroll
    for (int fj = 0; fj < 4; ++fj) {
        int kb = (fj * 16 + fr) * 64 + fk8;
        short8 kf0 = *(const short8*)(Kc + (kb ^ rsw));
        short8 kf1 = *(const short8*)(Kc + ((kb + 32) ^ rsw));
        accS0[fj] = mfma16(aqa0, kf0, accS0[fj]);
        accS1[fj] = mfma16(aqb0, kf0, accS1[fj]);
        accS0[fj] = mfma16(aqa1, kf1, accS0[fj]);
        accS1[fj] = mfma16(aqb1, kf1, accS1[fj]);
    }
    __builtin_amdgcn_s_setprio(0);

    // ---- gather CUR QR (written LAST iteration: no outstanding-write wait) ----
    float sc0[4][4], sc1[4][4];
#pragma unroll
    for (int fj = 0; fj < 4; ++fj) {
        int j_loc = fj * 16 + fr;
#pragma unroll
        for (int r = 0; r < 4; ++r) {
            int col = rgrp + r - j_loc + 63;   // in [0,78]
            sc0[fj][r] = accS0[fj][r] + b2f(curA[col * QRT + rgrp + r]);
            sc1[fj][r] = accS1[fj][r] + b2f(curB[col * QRT + rgrp + r]);
        }
    }
    if (mask_needed) {
#pragma unroll
        for (int fj = 0; fj < 4; ++fj) {
            int j_loc = fj * 16 + fr;
            if (j0 + j_loc >= S_) {
#pragma unroll
                for (int r = 0; r < 4; ++r) { sc0[fj][r] = -3e38f; sc1[fj][r] = -3e38f; }
            }
        }
    }

    // ---- spill NEXT iteration's QR (overlaps softmax below) ----
    __builtin_amdgcn_s_setprio(1);
    spill_qr(nxtA, rlnx, aqa0, aqa1, fr, rgrp);
    spill_qr(nxtB, rlnx + 1, aqb0, aqb1, fr, rgrp);
    __builtin_amdgcn_s_setprio(0);

    // ---- row max both (DPP) ----
    float pma[4], pmb[4];
#pragma unroll
    for (int r = 0; r < 4; ++r) {
        float m0 = fmaxf(fmaxf(sc0[0][r], sc0[1][r]), fmaxf(sc0[2][r], sc0[3][r]));
        float m1 = fmaxf(fmaxf(sc1[0][r], sc1[1][r]), fmaxf(sc1[2][r], sc1[3][r]));
        m0 = fmaxf(m0, DPPROR(m0, 1)); m1 = fmaxf(m1, DPPROR(m1, 1));
        m0 = fmaxf(m0, DPPROR(m0, 2)); m1 = fmaxf(m1, DPPROR(m1, 2));
        m0 = fmaxf(m0, DPPROR(m0, 4)); m1 = fmaxf(m1, DPPROR(m1, 4));
        m0 = fmaxf(m0, DPPROR(m0, 8)); m1 = fmaxf(m1, DPPROR(m1, 8));
        pma[r] = m0; pmb[r] = m1;
    }

    // ---- defer-max both ----
    float dmaxa = fmaxf(fmaxf(pma[0] - mra[0], pma[1] - mra[1]),
                        fmaxf(pma[2] - mra[2], pma[3] - mra[3]));
    if (!__all(dmaxa <= 8.0f)) {
#pragma unroll
        for (int r = 0; r < 4; ++r) {
            float mn = fmaxf(mra[r], pma[r]);
            float scl = __builtin_amdgcn_exp2f(mra[r] - mn);
            mra[r] = mn;
            lra[r] *= scl;
#pragma unroll
            for (int fd = 0; fd < 4; ++fd) accOa[fd][r] *= scl;
        }
    }
    float dmaxb = fmaxf(fmaxf(pmb[0] - mrb[0], pmb[1] - mrb[1]),
                        fmaxf(pmb[2] - mrb[2], pmb[3] - mrb[3]));
    if (!__all(dmaxb <= 8.0f)) {
#pragma unroll
        for (int r = 0; r < 4; ++r) {
            float mn = fmaxf(mrb[r], pmb[r]);
            float scl = __builtin_amdgcn_exp2f(mrb[r] - mn);
            mrb[r] = mn;
            lrb[r] *= scl;
#pragma unroll
            for (int fd = 0; fd < 4; ++fd) accOb[fd][r] *= scl;
        }
    }

    // ---- exp + P store both (P shares CUR region; gather already done) ----
    float rsa[4], rsb[4];
#pragma unroll
    for (int r = 0; r < 4; ++r) { rsa[r] = 0.f; rsb[r] = 0.f; }
#pragma unroll
    for (int fj = 0; fj < 4; ++fj) {
#pragma unroll
        for (int r = 0; r < 4; ++r) {
            float p0 = __builtin_amdgcn_exp2f(sc0[fj][r] - mra[r]);
            float p1 = __builtin_amdgcn_exp2f(sc1[fj][r] - mrb[r]);
            rsa[r] += p0; rsb[r] += p1;
            curA[(rgrp + r) * PW + fj * 16 + fr] = f2b_trunc(p0);
            curB[(rgrp + r) * PW + fj * 16 + fr] = f2b_trunc(p1);
        }
    }
#pragma unroll
    for (int r = 0; r < 4; ++r) {
        float s0 = rsa[r], s1 = rsb[r];
        s0 += DPPROR(s0, 1); s1 += DPPROR(s1, 1);
        s0 += DPPROR(s0, 2); s1 += DPPROR(s1, 2);
        s0 += DPPROR(s0, 4); s1 += DPPROR(s1, 4);
        s0 += DPPROR(s0, 8); s1 += DPPROR(s1, 8);
        lra[r] += s0; lrb[r] += s1;
    }

    // ---- PV both slabs, shared V fragments ----
    short8 apA0 = *(const short8*)(curA + fr * PW + fk8);
    short8 apA1 = *(const short8*)(curA + fr * PW + 32 + fk8);
    short8 apB0 = *(const short8*)(curB + fr * PW + fk8);
    short8 apB1 = *(const short8*)(curB + fr * PW + 32 + fk8);
    __builtin_amdgcn_s_setprio(1);
#pragma unroll
    for (int fd = 0; fd < 4; ++fd) {
        int vb = (fd * 16 + fr) * 64 + fk8;
        short8 vf0 = *(const short8*)(Vc + (vb ^ rsw));
        short8 vf1 = *(const short8*)(Vc + ((vb + 32) ^ rsw));
        accOa[fd] = mfma16(apA0, vf0, accOa[fd]);
        accOb[fd] = mfma16(apB0, vf0, accOb[fd]);
        accOa[fd] = mfma16(apA1, vf1, accOa[fd]);
        accOb[fd] = mfma16(apB1, vf1, accOb[fd]);
    }
    __builtin_amdgcn_s_setprio(0);
}

__global__ __launch_bounds__(256, 2) void attn_mfma(
        const unsigned short* __restrict__ qh, const unsigned short* __restrict__ kh,
        const unsigned short* __restrict__ vt, const unsigned short* __restrict__ relb,
        unsigned short* __restrict__ aout) {
    __shared__ __align__(16) unsigned short Ks[2][64 * 64];   // 16 KB
    __shared__ __align__(16) unsigned short Vs[2][64 * 64];   // 16 KB
    // 16 regions: (wave, slab, parity) -> 4*2*2; 36.9 KB total
    __shared__ __align__(16) unsigned short QP[16][QPR];

    int tid = threadIdx.x, lane = tid & 63, w = tid >> 6;
    int bid = blockIdx.x;                      // 512 blocks
    int swz = (bid & 7) * 64 + (bid >> 3);     // XCD-chunked, bijective (512 = 8*64)
    int bh = swz >> 3;                         // uniform across block
    int i0a = (((swz & 7) * 8) + 2 * w) * 16;  // slab a; slab b = i0a + 16
    int fr = lane & 15, fk8 = (lane >> 4) * 8, rgrp = (lane >> 4) * 4;
    int rsw = (fr & 7) << 3;                   // read-side XOR (ushort units)

    const unsigned short* kbase = kh + (size_t)bh * S_PAD * D_K;   // [i][d]
    const unsigned short* vtbase = vt + (size_t)bh * D_K * S_PAD;  // [d][i]

    const unsigned short* qpa = qh + ((size_t)bh * S_PAD + i0a + fr) * D_K + fk8;
    short8 aqa0 = *(const short8*)(qpa);
    short8 aqa1 = *(const short8*)(qpa + 32);
    const unsigned short* qpb = qpa + 16 * D_K;
    short8 aqb0 = *(const short8*)(qpb);
    short8 aqb1 = *(const short8*)(qpb + 32);

    f32x4 accOa[4], accOb[4];
    float mruna[4], lruna[4], mrunb[4], lrunb[4];
#pragma unroll
    for (int fd = 0; fd < 4; ++fd) { accOa[fd] = (f32x4)0.f; accOb[fd] = (f32x4)0.f; }
#pragma unroll
    for (int r = 0; r < 4; ++r) {
        mruna[r] = -3e38f; lruna[r] = 0.f;
        mrunb[r] = -3e38f; lrunb[r] = 0.f;
    }

    // region pointers: QP[(w*2+slab)*2 + parity]
    unsigned short* rgA[2] = { QP[(w * 2 + 0) * 2 + 0], QP[(w * 2 + 0) * 2 + 1] };
    unsigned short* rgB[2] = { QP[(w * 2 + 1) * 2 + 0], QP[(w * 2 + 1) * 2 + 1] };
    int row_in = lane >> 3, slot = lane & 7;

    auto stage = [&](int buf, int it2) {
        int j0s = it2 * 64;
#pragma unroll
        for (int cc = 0; cc < 2; ++cc) {
            int c = w * 2 + cc;
            int r = c * 8 + row_in;
            gload_lds16(kbase + (size_t)(j0s + r) * 64 + (slot ^ row_in) * 8,
                        &Ks[buf][c * 512]);
        }
#pragma unroll
        for (int cc = 0; cc < 2; ++cc) {
            int c = w * 2 + cc;
            int d = c * 8 + row_in;
            gload_lds16(vtbase + (size_t)d * S_PAD + j0s + (slot ^ row_in) * 8,
                        &Vs[buf][c * 512]);
        }
    };

    auto load_rl = [&](short8 rl[6][2], int jt) {
        int ub = i0a - jt * 64 + (S_ - D_K);
#pragma unroll
        for (int fu = 0; fu < 6; ++fu) {
            int u = ub + fu * 16 + fr;
            u = u < 0 ? 0 : (u > REL_ROWS - 1 ? REL_ROWS - 1 : u);
            const unsigned short* rp = relb + (size_t)u * D_K + fk8;
            rl[fu][0] = *(const short8*)(rp);
            rl[fu][1] = *(const short8*)(rp + 32);
        }
    };

    // ---- prologue: QR(0) into parity-0 regions; stage tile 0 ----
    {
        short8 rl0[6][2];
        load_rl(rl0, 0);
        spill_qr(rgA[0], rl0, aqa0, aqa1, fr, rgrp);
        spill_qr(rgB[0], rl0 + 1, aqb0, aqb1, fr, rgrp);
    }
    stage(0, 0);
    __syncthreads();   // tile 0 + QR(0) visible

    for (int it = 0; it < 16; ++it) {
        int cur = it & 1, j0 = it * 64;
        bool mask_needed = (j0 + 63 >= S_);

        // rel fragments for NEXT iteration, issued BEFORE stage (counted vmcnt)
        short8 rl[6][2];
        load_rl(rl, it + 1);   // it=15: clamped reads, result unused
        __builtin_amdgcn_sched_barrier(0);

        if (it < 15) stage(cur ^ 1, it + 1);  // prefetch next K/V tile

        attn_pair(Ks[cur], Vs[cur],
                  rgA[cur], rgB[cur], rgA[cur ^ 1], rgB[cur ^ 1], rl,
                  aqa0, aqa1, aqb0, aqb1, accOa, accOb,
                  mruna, lruna, mrunb, lrunb,
                  mask_needed, j0, fr, fk8, rgrp, rsw);

        __syncthreads();   // next tile landed; all waves done with Ks/Vs[cur]
    }

    // ---- normalize + store both slabs ----
    int b_ = bh >> 4, h = bh & 15;
#pragma unroll
    for (int r = 0; r < 4; ++r) {
        float inva = 1.0f / lruna[r];
        float invb = 1.0f / lrunb[r];
        int ma = b_ * S_PAD + i0a + rgrp + r;
        int mb = ma + 16;
#pragma unroll
        for (int fd = 0; fd < 4; ++fd) {
            int c = h * D_K + fd * 16 + fr;
            aout[(size_t)ma * D_MODEL + c] = f2b(accOa[fd][r] * inva);
            aout[(size_t)mb * D_MODEL + c] = f2b(accOb[fd][r] * invb);
        }
    }
}

extern "C" void kernel_launch(void* const* d_in, const int* in_sizes, int n_in,
                              void* d_out, int out_size, void* d_ws, size_t ws_size,
                              hipStream_t stream) {
    const float* q    = (const float*)d_in[0];
    const float* k    = (const float*)d_in[1];
    const float* v    = (const float*)d_in[2];
    const float* ln_g = (const float*)d_in[3];
    const float* ln_b = (const float*)d_in[4];
    const float* wq   = (const float*)d_in[5];
    const float* bq   = (const float*)d_in[6];
    const float* wk   = (const float*)d_in[7];
    const float* bk   = (const float*)d_in[8];
    const float* wv   = (const float*)d_in[9];
    const float* bv   = (const float*)d_in[10];
    const float* wo   = (const float*)d_in[11];
    const float* bo   = (const float*)d_in[12];
    const float* rel  = (const float*)d_in[13];
    float* out = (float*)d_out;

    const size_t TSZ = (size_t)M_PAD * D_MODEL;     // 4,194,304 ushorts
    unsigned short* ws   = (unsigned short*)d_ws;
    unsigned short* qn   = ws;
    unsigned short* kn   = qn + TSZ;
    unsigned short* vn   = kn + TSZ;
    unsigned short* qh   = vn + TSZ;
    unsigned short* kh   = qh + TSZ;
    unsigned short* vt   = kh + TSZ;
    unsigned short* aout = vt + TSZ;
    unsigned short* wqb  = aout + TSZ;
    unsigned short* wkb  = wqb + 1024 * 1024;
    unsigned short* wvb  = wkb + 1024 * 1024;
    unsigned short* wob  = wvb + 1024 * 1024;
    unsigned short* relb = wob + 1024 * 1024;

    // weights cvt + 3 LayerNorms in ONE launch
    prep_all<<<5120 + 3 * 4096, 256, 0, stream>>>(
        wq, wk, wv, wo, rel, wqb, wkb, wvb, wob, relb,
        q, k, v, ln_g, ln_b, qn, kn, vn);

    gemm_qkv<<<dim3(8, 32, 3), 256, 0, stream>>>(qn, kn, vn, wqb, wkb, wvb,
                                                 bq, bk, bv, qh, kh, vt);

    attn_mfma<<<512, 256, 0, stream>>>(qh, kh, vt, relb, aout);

    gemm_out<<<dim3(8, 32), 256, 0, stream>>>(aout, wob, bo, q, out);
}

// Round 19
// 163.374 us; speedup vs baseline: 1.2010x; 1.2010x over previous
//
#include <hip/hip_runtime.h>
#include <hip/hip_bf16.h>

#define D_MODEL 1024
#define N_HEAD  16
#define D_K     64
#define MAX_LEN 1000
#define B_      4
#define S_      1000
#define S_PAD   1024
#define M_PAD   (B_ * S_PAD)       // 4096
#define M_REAL  (B_ * S_)          // 4000
#define LN_EPS  1e-5f
#define SCALE_L2E 0.1803368801111204f   // 0.125 * log2(e)
#define REL_ROWS (2*MAX_LEN-1)     // 1999

typedef __attribute__((ext_vector_type(8))) short short8;
typedef __attribute__((ext_vector_type(4))) float f32x4;

__device__ __forceinline__ unsigned short f2b(float f) {
    unsigned u = __builtin_bit_cast(unsigned, f);
    u = (u + 0x7FFFu + ((u >> 16) & 1u)) >> 16;
    return (unsigned short)u;
}

__device__ __forceinline__ unsigned short f2b_trunc(float f) {
    return (unsigned short)(__builtin_bit_cast(unsigned, f) >> 16);
}

__device__ __forceinline__ float b2f(unsigned short u) {
    return __builtin_bit_cast(float, (unsigned)u << 16);
}

__device__ __forceinline__ f32x4 mfma16(short8 a, short8 b, f32x4 c) {
    return __builtin_amdgcn_mfma_f32_16x16x32_bf16(a, b, c, 0, 0, 0);
}

__device__ __forceinline__ void gload_lds16(const void* g, void* l) {
    __builtin_amdgcn_global_load_lds(
        (const __attribute__((address_space(1))) unsigned int*)g,
        (__attribute__((address_space(3))) unsigned int*)l, 16, 0, 0);
}

// DPP row_ror rotation within 16-lane rows (VALU, not LDS pipe)
#define DPPROR(x, S) __builtin_bit_cast(float, __builtin_amdgcn_update_dpp( \
        0, __builtin_bit_cast(int, (x)), 0x120 | (S), 0xF, 0xF, false))

// ---------------- merged cvt (5 weight tensors) + LayerNorm x3, ONE launch ----------------
__global__ void prep_all(const float* __restrict__ wq, const float* __restrict__ wk,
                         const float* __restrict__ wv, const float* __restrict__ wo,
                         const float* __restrict__ rel,
                         unsigned short* __restrict__ wqb, unsigned short* __restrict__ wkb,
                         unsigned short* __restrict__ wvb, unsigned short* __restrict__ wob,
                         unsigned short* __restrict__ relb,
                         const float* __restrict__ xq, const float* __restrict__ xk,
                         const float* __restrict__ xv, const float* __restrict__ g,
                         const float* __restrict__ beta,
                         unsigned short* __restrict__ yq, unsigned short* __restrict__ yk,
                         unsigned short* __restrict__ yv) {
    __shared__ float rs[4], rq[4];
    int bid = blockIdx.x;
    int tid = threadIdx.x;
    if (bid < 5120) {
        int y = bid >> 10;
        const float* in; unsigned short* out; int n4;
        switch (y) {
            case 0: in = wq; out = wqb; n4 = 262144; break;
            case 1: in = wk; out = wkb; n4 = 262144; break;
            case 2: in = wv; out = wvb; n4 = 262144; break;
            case 3: in = wo; out = wob; n4 = 262144; break;
            default: in = rel; out = relb; n4 = REL_ROWS * D_K / 4; break;
        }
        int i = (bid & 1023) * 256 + tid;
        if (i >= n4) return;
        float4 v = ((const float4*)in)[i];
        ushort4 o;
        o.x = f2b(v.x); o.y = f2b(v.y); o.z = f2b(v.z); o.w = f2b(v.w);
        ((ushort4*)out)[i] = o;
        return;
    }
    int r2 = bid - 5120;
    int which = r2 >> 12;          // 0..2
    int r = r2 & 4095;             // padded row index
    const float* x = which == 0 ? xq : which == 1 ? xk : xv;
    unsigned short* y = which == 0 ? yq : which == 1 ? yk : yv;
    int b = r >> 10, i = r & 1023;
    unsigned short* yr = y + (size_t)r * D_MODEL;
    if (i >= S_) {
#pragma unroll
        for (int l = 0; l < 4; ++l) yr[tid + l * 256] = 0;
        return;
    }
    const float* xr = x + ((size_t)b * S_ + i) * D_MODEL;
    float v[4];
    float s = 0.f, sq = 0.f;
#pragma unroll
    for (int l = 0; l < 4; ++l) {
        v[l] = xr[tid + l * 256];
        s += v[l];
        sq += v[l] * v[l];
    }
#pragma unroll
    for (int o = 32; o > 0; o >>= 1) {
        s += __shfl_down(s, o, 64);
        sq += __shfl_down(sq, o, 64);
    }
    if ((tid & 63) == 0) { rs[tid >> 6] = s; rq[tid >> 6] = sq; }
    __syncthreads();
    if (tid == 0) {
        rs[0] = rs[0] + rs[1] + rs[2] + rs[3];
        rq[0] = rq[0] + rq[1] + rq[2] + rq[3];
    }
    __syncthreads();
    float mu = rs[0] * (1.0f / D_MODEL);
    float var = rq[0] * (1.0f / D_MODEL) - mu * mu;
    float rstd = rsqrtf(var + LN_EPS);
#pragma unroll
    for (int l = 0; l < 4; ++l) {
        int c = tid + l * 256;
        yr[c] = f2b((v[l] - mu) * rstd * g[c] + beta[c]);
    }
}

// ---------------- GEMM core: double-buffered K-loop ----------------
// MODE 0: head layout; MODE 3: head layout PRESCALED by SCALE_L2E (for Q);
// MODE 1: transposed head; MODE 2: fp32 +resid.
template<int MODE>
__device__ __forceinline__ void gemm_body(
        const unsigned short* __restrict__ X, const unsigned short* __restrict__ W,
        const float* __restrict__ bias, const float* __restrict__ resid,
        unsigned short* __restrict__ Yb, float* __restrict__ Yf,
        unsigned short* As, unsigned short* Bs, int row0, int col0) {
    int tid = threadIdx.x;
    int lane = tid & 63, w = tid >> 6;
    int wr = w >> 1, wc = w & 1;
    int fr = lane & 15, fk = (lane >> 4) * 8;

    f32x4 acc[4][4];
#pragma unroll
    for (int fm = 0; fm < 4; ++fm)
#pragma unroll
        for (int fn = 0; fn < 4; ++fn) acc[fm][fn] = (f32x4)0.f;

    int c0 = (w * 2 + 0) * 64 + lane;
    int c1 = (w * 2 + 1) * 64 + lane;
    const unsigned short* xs0 = X + (size_t)(row0 + (c0 >> 2)) * 1024 + (c0 & 3) * 8;
    const unsigned short* xs1 = X + (size_t)(row0 + (c1 >> 2)) * 1024 + (c1 & 3) * 8;
    const unsigned short* ws0 = W + (size_t)(col0 + (c0 >> 2)) * 1024 + (c0 & 3) * 8;
    const unsigned short* ws1 = W + (size_t)(col0 + (c1 >> 2)) * 1024 + (c1 & 3) * 8;
    int do0 = (w * 2 + 0) * 512;
    int do1 = (w * 2 + 1) * 512;

    auto stage = [&](int buf, int k0) {
        gload_lds16(xs0 + k0, As + buf * 4096 + do0);
        gload_lds16(xs1 + k0, As + buf * 4096 + do1);
        gload_lds16(ws0 + k0, Bs + buf * 4096 + do0);
        gload_lds16(ws1 + k0, Bs + buf * 4096 + do1);
    };

    stage(0, 0);

    for (int it = 0; it < 32; ++it) {
        __syncthreads();
        if (it < 31) stage((it & 1) ^ 1, (it + 1) * 32);

        const unsigned short* Ab = As + (it & 1) * 4096;
        const unsigned short* Bb = Bs + (it & 1) * 4096;
        short8 a[4], b[4];
#pragma unroll
        for (int fm = 0; fm < 4; ++fm)
            a[fm] = *(const short8*)(Ab + (wr * 64 + fm * 16 + fr) * 32 + fk);
#pragma unroll
        for (int fn = 0; fn < 4; ++fn)
            b[fn] = *(const short8*)(Bb + (wc * 64 + fn * 16 + fr) * 32 + fk);
#pragma unroll
        for (int fm = 0; fm < 4; ++fm)
#pragma unroll
            for (int fn = 0; fn < 4; ++fn)
                acc[fm][fn] = mfma16(a[fm], b[fn], acc[fm][fn]);
    }

#pragma unroll
    for (int fm = 0; fm < 4; ++fm) {
#pragma unroll
        for (int fn = 0; fn < 4; ++fn) {
            int cg = col0 + wc * 64 + fn * 16 + fr;
            float bv = bias[cg];
#pragma unroll
            for (int r = 0; r < 4; ++r) {
                int rg = row0 + wr * 64 + fm * 16 + (lane >> 4) * 4 + r;
                float val = acc[fm][fn][r] + bv;
                int b_ = rg >> 10, i = rg & 1023;
                if (MODE == 0 || MODE == 3) {
                    if (MODE == 3) val *= SCALE_L2E;
                    int h = cg >> 6, d = cg & 63;
                    Yb[(((size_t)(b_ * N_HEAD + h)) * S_PAD + i) * D_K + d] = f2b(val);
                } else if (MODE == 1) {
                    int h = cg >> 6, d = cg & 63;
                    Yb[(((size_t)(b_ * N_HEAD + h)) * D_K + d) * S_PAD + i] = f2b(val);
                } else {
                    if (i < S_) {
                        size_t orow = (size_t)b_ * S_ + i;
                        Yf[orow * 1024 + cg] = val + resid[orow * 1024 + cg];
                    }
                }
            }
        }
    }
}

// merged Q/K/V projections: grid (8, 32, 3); Q prescaled (MODE 3)
__global__ __launch_bounds__(256) void gemm_qkv(
        const unsigned short* __restrict__ qn, const unsigned short* __restrict__ kn,
        const unsigned short* __restrict__ vn,
        const unsigned short* __restrict__ wqb, const unsigned short* __restrict__ wkb,
        const unsigned short* __restrict__ wvb,
        const float* __restrict__ bq, const float* __restrict__ bk,
        const float* __restrict__ bv,
        unsigned short* __restrict__ qh, unsigned short* __restrict__ kh,
        unsigned short* __restrict__ vt) {
    __shared__ __align__(16) unsigned short As[2][128 * 32];
    __shared__ __align__(16) unsigned short Bs[2][128 * 32];
    int fid = blockIdx.x + (blockIdx.y << 3) + (blockIdx.z << 8);   // [0,768)
    int swz = (fid & 7) * 96 + (fid >> 3);                          // bijective
    int bz = swz >> 8;
    int rem = swz & 255;
    int row0 = (rem >> 3) * 128, col0 = (rem & 7) * 128;
    if (bz == 0)
        gemm_body<3>(qn, wqb, bq, nullptr, qh, nullptr, As[0], Bs[0], row0, col0);
    else if (bz == 1)
        gemm_body<0>(kn, wkb, bk, nullptr, kh, nullptr, As[0], Bs[0], row0, col0);
    else
        gemm_body<1>(vn, wvb, bv, nullptr, vt, nullptr, As[0], Bs[0], row0, col0);
}

// final output projection + residual
__global__ __launch_bounds__(256) void gemm_out(
        const unsigned short* __restrict__ X, const unsigned short* __restrict__ W,
        const float* __restrict__ bias, const float* __restrict__ resid,
        float* __restrict__ Yf) {
    __shared__ __align__(16) unsigned short As[2][128 * 32];
    __shared__ __align__(16) unsigned short Bs[2][128 * 32];
    int fid = blockIdx.x + (blockIdx.y << 3);       // [0,256)
    int swz = (fid & 7) * 32 + (fid >> 3);          // bijective
    int row0 = (swz >> 3) * 128, col0 = (swz & 7) * 128;
    gemm_body<2>(X, W, bias, resid, nullptr, Yf, As[0], Bs[0], row0, col0);
}

// ---------------- Flash attention: FUSED two-slab interleave (r17, best) ----------------
#define QRT 20
#define QPW 1600  // per-(wave,slab) QP region: 80 cols * 20
#define PW  72    // P scratch stride (64 used), same region (disjoint lifetime)
__device__ __forceinline__ void attn_pair(
        const unsigned short* __restrict__ Kc, const unsigned short* __restrict__ Vc,
        unsigned short* __restrict__ qpA, unsigned short* __restrict__ qpB,
        const short8 (*rl)[2],     // 6 fragments: a uses 0..4, b uses 1..5
        short8 aqa0, short8 aqa1, short8 aqb0, short8 aqb1,
        f32x4* accOa, f32x4* accOb,
        float* mra, float* lra, float* mrb, float* lrb,
        bool mask_needed, int j0, int fr, int fk8, int rgrp, int rsw) {
    // ---- QK^T both slabs, shared K fragments ----
    f32x4 accS0[4], accS1[4];
#pragma unroll
    for (int fj = 0; fj < 4; ++fj) { accS0[fj] = (f32x4)0.f; accS1[fj] = (f32x4)0.f; }
    __builtin_amdgcn_s_setprio(1);
#pragma unroll
    for (int fj = 0; fj < 4; ++fj) {
        int kb = (fj * 16 + fr) * 64 + fk8;
        short8 kf0 = *(const short8*)(Kc + (kb ^ rsw));
        short8 kf1 = *(const short8*)(Kc + ((kb + 32) ^ rsw));
        accS0[fj] = mfma16(aqa0, kf0, accS0[fj]);
        accS1[fj] = mfma16(aqb0, kf0, accS1[fj]);
        accS0[fj] = mfma16(aqa1, kf1, accS0[fj]);
        accS1[fj] = mfma16(aqb1, kf1, accS1[fj]);
    }
    // ---- QR both slabs; spill b64 (truncated bf16) ----
#pragma unroll
    for (int fu = 0; fu < 5; ++fu) {
        f32x4 qr = (f32x4)0.f;
        qr = mfma16(aqa0, rl[fu][0], qr);
        qr = mfma16(aqa1, rl[fu][1], qr);
        unsigned lo = ((unsigned)f2b_trunc(qr[1]) << 16) | f2b_trunc(qr[0]);
        unsigned hi = ((unsigned)f2b_trunc(qr[3]) << 16) | f2b_trunc(qr[2]);
        *(uint2*)(qpA + (fu * 16 + fr) * QRT + rgrp) = uint2{lo, hi};
    }
#pragma unroll
    for (int fu = 0; fu < 5; ++fu) {
        f32x4 qr = (f32x4)0.f;
        qr = mfma16(aqb0, rl[fu + 1][0], qr);
        qr = mfma16(aqb1, rl[fu + 1][1], qr);
        unsigned lo = ((unsigned)f2b_trunc(qr[1]) << 16) | f2b_trunc(qr[0]);
        unsigned hi = ((unsigned)f2b_trunc(qr[3]) << 16) | f2b_trunc(qr[2]);
        *(uint2*)(qpB + (fu * 16 + fr) * QRT + rgrp) = uint2{lo, hi};
    }
    __builtin_amdgcn_s_setprio(0);

    // ---- assemble scores both slabs (Q prescaled: no multiply) ----
    float sc0[4][4], sc1[4][4];
#pragma unroll
    for (int fj = 0; fj < 4; ++fj) {
        int j_loc = fj * 16 + fr;
#pragma unroll
        for (int r = 0; r < 4; ++r) {
            int col = rgrp + r - j_loc + 63;   // in [0,78]
            sc0[fj][r] = accS0[fj][r] + b2f(qpA[col * QRT + rgrp + r]);
            sc1[fj][r] = accS1[fj][r] + b2f(qpB[col * QRT + rgrp + r]);
        }
    }
    if (mask_needed) {
#pragma unroll
        for (int fj = 0; fj < 4; ++fj) {
            int j_loc = fj * 16 + fr;
            if (j0 + j_loc >= S_) {
#pragma unroll
                for (int r = 0; r < 4; ++r) { sc0[fj][r] = -3e38f; sc1[fj][r] = -3e38f; }
            }
        }
    }

    // ---- row max both (DPP) ----
    float pma[4], pmb[4];
#pragma unroll
    for (int r = 0; r < 4; ++r) {
        float m0 = fmaxf(fmaxf(sc0[0][r], sc0[1][r]), fmaxf(sc0[2][r], sc0[3][r]));
        float m1 = fmaxf(fmaxf(sc1[0][r], sc1[1][r]), fmaxf(sc1[2][r], sc1[3][r]));
        m0 = fmaxf(m0, DPPROR(m0, 1)); m1 = fmaxf(m1, DPPROR(m1, 1));
        m0 = fmaxf(m0, DPPROR(m0, 2)); m1 = fmaxf(m1, DPPROR(m1, 2));
        m0 = fmaxf(m0, DPPROR(m0, 4)); m1 = fmaxf(m1, DPPROR(m1, 4));
        m0 = fmaxf(m0, DPPROR(m0, 8)); m1 = fmaxf(m1, DPPROR(m1, 8));
        pma[r] = m0; pmb[r] = m1;
    }

    // ---- defer-max both ----
    float dmaxa = fmaxf(fmaxf(pma[0] - mra[0], pma[1] - mra[1]),
                        fmaxf(pma[2] - mra[2], pma[3] - mra[3]));
    if (!__all(dmaxa <= 8.0f)) {
#pragma unroll
        for (int r = 0; r < 4; ++r) {
            float mn = fmaxf(mra[r], pma[r]);
            float scl = __builtin_amdgcn_exp2f(mra[r] - mn);
            mra[r] = mn;
            lra[r] *= scl;
#pragma unroll
            for (int fd = 0; fd < 4; ++fd) accOa[fd][r] *= scl;
        }
    }
    float dmaxb = fmaxf(fmaxf(pmb[0] - mrb[0], pmb[1] - mrb[1]),
                        fmaxf(pmb[2] - mrb[2], pmb[3] - mrb[3]));
    if (!__all(dmaxb <= 8.0f)) {
#pragma unroll
        for (int r = 0; r < 4; ++r) {
            float mn = fmaxf(mrb[r], pmb[r]);
            float scl = __builtin_amdgcn_exp2f(mrb[r] - mn);
            mrb[r] = mn;
            lrb[r] *= scl;
#pragma unroll
            for (int fd = 0; fd < 4; ++fd) accOb[fd][r] *= scl;
        }
    }

    // ---- exp + P store both; row-sum via DPP ----
    float rsa[4], rsb[4];
#pragma unroll
    for (int r = 0; r < 4; ++r) { rsa[r] = 0.f; rsb[r] = 0.f; }
#pragma unroll
    for (int fj = 0; fj < 4; ++fj) {
#pragma unroll
        for (int r = 0; r < 4; ++r) {
            float p0 = __builtin_amdgcn_exp2f(sc0[fj][r] - mra[r]);
            float p1 = __builtin_amdgcn_exp2f(sc1[fj][r] - mrb[r]);
            rsa[r] += p0; rsb[r] += p1;
            qpA[(rgrp + r) * PW + fj * 16 + fr] = f2b_trunc(p0);
            qpB[(rgrp + r) * PW + fj * 16 + fr] = f2b_trunc(p1);
        }
    }
#pragma unroll
    for (int r = 0; r < 4; ++r) {
        float s0 = rsa[r], s1 = rsb[r];
        s0 += DPPROR(s0, 1); s1 += DPPROR(s1, 1);
        s0 += DPPROR(s0, 2); s1 += DPPROR(s1, 2);
        s0 += DPPROR(s0, 4); s1 += DPPROR(s1, 4);
        s0 += DPPROR(s0, 8); s1 += DPPROR(s1, 8);
        lra[r] += s0; lrb[r] += s1;
    }

    // ---- PV both slabs, shared V fragments ----
    short8 apA0 = *(const short8*)(qpA + fr * PW + fk8);
    short8 apA1 = *(const short8*)(qpA + fr * PW + 32 + fk8);
    short8 apB0 = *(const short8*)(qpB + fr * PW + fk8);
    short8 apB1 = *(const short8*)(qpB + fr * PW + 32 + fk8);
    __builtin_amdgcn_s_setprio(1);
#pragma unroll
    for (int fd = 0; fd < 4; ++fd) {
        int vb = (fd * 16 + fr) * 64 + fk8;
        short8 vf0 = *(const short8*)(Vc + (vb ^ rsw));
        short8 vf1 = *(const short8*)(Vc + ((vb + 32) ^ rsw));
        accOa[fd] = mfma16(apA0, vf0, accOa[fd]);
        accOb[fd] = mfma16(apB0, vf0, accOb[fd]);
        accOa[fd] = mfma16(apA1, vf1, accOa[fd]);
        accOb[fd] = mfma16(apB1, vf1, accOb[fd]);
    }
    __builtin_amdgcn_s_setprio(0);
}

__global__ __launch_bounds__(256, 2) void attn_mfma(
        const unsigned short* __restrict__ qh, const unsigned short* __restrict__ kh,
        const unsigned short* __restrict__ vt, const unsigned short* __restrict__ relb,
        unsigned short* __restrict__ aout) {
    __shared__ __align__(16) unsigned short Ks[2][64 * 64];   // 16 KB
    __shared__ __align__(16) unsigned short Vs[2][64 * 64];   // 16 KB
    __shared__ __align__(16) unsigned short QP[8][QPW];       // 25 KB

    int tid = threadIdx.x, lane = tid & 63, w = tid >> 6;
    int bid = blockIdx.x;                      // 512 blocks
    int swz = (bid & 7) * 64 + (bid >> 3);     // XCD-chunked, bijective (512 = 8*64)
    int bh = swz >> 3;                         // uniform across block
    int i0a = (((swz & 7) * 8) + 2 * w) * 16;  // slab a; slab b = i0a + 16
    int fr = lane & 15, fk8 = (lane >> 4) * 8, rgrp = (lane >> 4) * 4;
    int rsw = (fr & 7) << 3;                   // read-side XOR (ushort units)

    const unsigned short* kbase = kh + (size_t)bh * S_PAD * D_K;   // [i][d]
    const unsigned short* vtbase = vt + (size_t)bh * D_K * S_PAD;  // [d][i]

    const unsigned short* qpa = qh + ((size_t)bh * S_PAD + i0a + fr) * D_K + fk8;
    short8 aqa0 = *(const short8*)(qpa);
    short8 aqa1 = *(const short8*)(qpa + 32);
    const unsigned short* qpb = qpa + 16 * D_K;
    short8 aqb0 = *(const short8*)(qpb);
    short8 aqb1 = *(const short8*)(qpb + 32);

    f32x4 accOa[4], accOb[4];
    float mruna[4], lruna[4], mrunb[4], lrunb[4];
#pragma unroll
    for (int fd = 0; fd < 4; ++fd) { accOa[fd] = (f32x4)0.f; accOb[fd] = (f32x4)0.f; }
#pragma unroll
    for (int r = 0; r < 4; ++r) {
        mruna[r] = -3e38f; lruna[r] = 0.f;
        mrunb[r] = -3e38f; lrunb[r] = 0.f;
    }

    unsigned short* qpA = QP[w];          // slab a scratch
    unsigned short* qpB = QP[4 + w];      // slab b scratch
    int row_in = lane >> 3, slot = lane & 7;

    auto stage = [&](int buf, int it2) {
        int j0s = it2 * 64;
#pragma unroll
        for (int cc = 0; cc < 2; ++cc) {
            int c = w * 2 + cc;
            int r = c * 8 + row_in;
            gload_lds16(kbase + (size_t)(j0s + r) * 64 + (slot ^ row_in) * 8,
                        &Ks[buf][c * 512]);
        }
#pragma unroll
        for (int cc = 0; cc < 2; ++cc) {
            int c = w * 2 + cc;
            int d = c * 8 + row_in;
            gload_lds16(vtbase + (size_t)d * S_PAD + j0s + (slot ^ row_in) * 8,
                        &Vs[buf][c * 512]);
        }
    };

    stage(0, 0);
    __syncthreads();   // tile 0 landed

    for (int it = 0; it < 16; ++it) {
        int cur = it & 1, j0 = it * 64;
        bool mask_needed = (j0 + 63 >= S_);

        // ---- rel fragments for BOTH slabs issued BEFORE stage ----
        short8 rl[6][2];
        int ub = i0a - j0 + (S_ - D_K);
#pragma unroll
        for (int fu = 0; fu < 6; ++fu) {
            int u = ub + fu * 16 + fr;
            u = u < 0 ? 0 : (u > REL_ROWS - 1 ? REL_ROWS - 1 : u);
            const unsigned short* rp = relb + (size_t)u * D_K + fk8;
            rl[fu][0] = *(const short8*)(rp);
            rl[fu][1] = *(const short8*)(rp + 32);
        }
        __builtin_amdgcn_sched_barrier(0);   // pin rel loads ahead of stage issue

        if (it < 15) stage(cur ^ 1, it + 1);  // prefetch next tile (other buffer)

        attn_pair(Ks[cur], Vs[cur], qpA, qpB, rl,
                  aqa0, aqa1, aqb0, aqb1, accOa, accOb,
                  mruna, lruna, mrunb, lrunb,
                  mask_needed, j0, fr, fk8, rgrp, rsw);

        __syncthreads();   // next tile landed; all waves done with Ks/Vs[cur]
    }

    // ---- normalize + store both slabs ----
    int b_ = bh >> 4, h = bh & 15;
#pragma unroll
    for (int r = 0; r < 4; ++r) {
        float inva = 1.0f / lruna[r];
        float invb = 1.0f / lrunb[r];
        int ma = b_ * S_PAD + i0a + rgrp + r;
        int mb = ma + 16;
#pragma unroll
        for (int fd = 0; fd < 4; ++fd) {
            int c = h * D_K + fd * 16 + fr;
            aout[(size_t)ma * D_MODEL + c] = f2b(accOa[fd][r] * inva);
            aout[(size_t)mb * D_MODEL + c] = f2b(accOb[fd][r] * invb);
        }
    }
}

extern "C" void kernel_launch(void* const* d_in, const int* in_sizes, int n_in,
                              void* d_out, int out_size, void* d_ws, size_t ws_size,
                              hipStream_t stream) {
    const float* q    = (const float*)d_in[0];
    const float* k    = (const float*)d_in[1];
    const float* v    = (const float*)d_in[2];
    const float* ln_g = (const float*)d_in[3];
    const float* ln_b = (const float*)d_in[4];
    const float* wq   = (const float*)d_in[5];
    const float* bq   = (const float*)d_in[6];
    const float* wk   = (const float*)d_in[7];
    const float* bk   = (const float*)d_in[8];
    const float* wv   = (const float*)d_in[9];
    const float* bv   = (const float*)d_in[10];
    const float* wo   = (const float*)d_in[11];
    const float* bo   = (const float*)d_in[12];
    const float* rel  = (const float*)d_in[13];
    float* out = (float*)d_out;

    const size_t TSZ = (size_t)M_PAD * D_MODEL;     // 4,194,304 ushorts
    unsigned short* ws   = (unsigned short*)d_ws;
    unsigned short* qn   = ws;
    unsigned short* kn   = qn + TSZ;
    unsigned short* vn   = kn + TSZ;
    unsigned short* qh   = vn + TSZ;
    unsigned short* kh   = qh + TSZ;
    unsigned short* vt   = kh + TSZ;
    unsigned short* aout = vt + TSZ;
    unsigned short* wqb  = aout + TSZ;
    unsigned short* wkb  = wqb + 1024 * 1024;
    unsigned short* wvb  = wkb + 1024 * 1024;
    unsigned short* wob  = wvb + 1024 * 1024;
    unsigned short* relb = wob + 1024 * 1024;

    // weights cvt + 3 LayerNorms in ONE launch
    prep_all<<<5120 + 3 * 4096, 256, 0, stream>>>(
        wq, wk, wv, wo, rel, wqb, wkb, wvb, wob, relb,
        q, k, v, ln_g, ln_b, qn, kn, vn);

    gemm_qkv<<<dim3(8, 32, 3), 256, 0, stream>>>(qn, kn, vn, wqb, wkb, wvb,
                                                 bq, bk, bv, qh, kh, vt);

    attn_mfma<<<512, 256, 0, stream>>>(qh, kh, vt, relb, aout);

    gemm_out<<<dim3(8, 32), 256, 0, stream>>>(aout, wob, bo, q, out);
}